// Round 1
// baseline (1457.570 us; speedup 1.0000x reference)
//
#include <hip/hip_runtime.h>
#include <math.h>

// WindowAttention: B=2048, C=256, H=8, d_k=32, wh=ww=7 -> L=49, nW=64.
// NOTE: reference sets v = k (torch bug kept): values come from K.
// Outputs concatenated: score (2048*256*49 f32) then attn (2048*8*49*49 f32).

#define LW 49      // window length
#define LP 52      // padded stride (multiple of 4 -> 16B-aligned float4 in LDS)
#define DK 32      // head dim
#define NH 8

__global__ __launch_bounds__(256) void wa_kernel(
    const float* __restrict__ q, const float* __restrict__ k,
    const float* __restrict__ mask, const float* __restrict__ table,
    const int* __restrict__ idx,
    float* __restrict__ score_out, float* __restrict__ attn_out)
{
    __shared__ float sQ[DK * LP];
    __shared__ float sK[DK * LP];
    __shared__ float sS[LP * LP];   // score matrix, rows 0..48 valid, pad cols zeroed

    const int tid = threadIdx.x;
    const int bh  = blockIdx.x;          // b*8 + h
    const int b   = bh >> 3;
    const int h   = bh & 7;

    // q/k head slice is contiguous: offset (b*256 + h*32)*49 = bh*1568
    const float* qp = q + (size_t)bh * (DK * LW);
    const float* kp = k + (size_t)bh * (DK * LW);

    // ---- Phase 0: stage Q,K into LDS with stride padding 49 -> 52 ----
    for (int i = tid; i < DK * LW; i += 256) {
        int c = i / LW;
        int t = i - c * LW;
        sQ[c * LP + t] = qp[i];
        sK[c * LP + t] = kp[i];
    }
    if (tid < DK * 3) {                  // zero pad columns 49..51
        int c = tid / 3, j = tid - (tid / 3) * 3;
        sQ[c * LP + LW + j] = 0.f;
        sK[c * LP + LW + j] = 0.f;
    }
    __syncthreads();

    // ---- Phase 1: S = scale*Q^T K + bias + mask  (13x13 tiles of 4x4) ----
    const float scale = 0.17677669529663687f;   // 32^-0.5
    const float* mrow = mask + (size_t)(b & 63) * (LW * LW);

    if (tid < 169) {
        const int r  = tid / 13;
        const int cc = tid - r * 13;
        const int t0 = r * 4;
        const int s0 = cc * 4;
        float acc[4][4];
        #pragma unroll
        for (int i = 0; i < 4; i++)
            #pragma unroll
            for (int j = 0; j < 4; j++) acc[i][j] = 0.f;

        #pragma unroll 8
        for (int c = 0; c < DK; c++) {
            const float4 qv = *(const float4*)&sQ[c * LP + t0];
            const float4 kv = *(const float4*)&sK[c * LP + s0];
            const float qa[4] = {qv.x, qv.y, qv.z, qv.w};
            const float ka[4] = {kv.x, kv.y, kv.z, kv.w};
            #pragma unroll
            for (int i = 0; i < 4; i++)
                #pragma unroll
                for (int j = 0; j < 4; j++)
                    acc[i][j] = fmaf(qa[i], ka[j], acc[i][j]);
        }
        #pragma unroll
        for (int i = 0; i < 4; i++) {
            const int t = t0 + i;
            if (t < LW) {
                #pragma unroll
                for (int j = 0; j < 4; j++) {
                    const int s = s0 + j;
                    float val = 0.f;                     // zero pads (cols 49..51)
                    if (s < LW) {
                        const int e = t * LW + s;
                        val = fmaf(acc[i][j], scale,
                                   table[idx[e] * NH + h] + mrow[e]);
                    }
                    sS[t * LP + s] = val;
                }
            }
        }
    }
    __syncthreads();

    // ---- Phase 2: row softmax (one row per wave iteration) + attn write ----
    const int lane = tid & 63;
    const int wv   = tid >> 6;
    float* attn_base = attn_out + (size_t)bh * (LW * LW);
    for (int t = wv; t < LW; t += 4) {
        const float x = (lane < LW) ? sS[t * LP + lane] : -INFINITY;
        float m = x;
        #pragma unroll
        for (int off = 32; off >= 1; off >>= 1)
            m = fmaxf(m, __shfl_xor(m, off, 64));
        const float e = (lane < LW) ? __expf(x - m) : 0.f;
        float ssum = e;
        #pragma unroll
        for (int off = 32; off >= 1; off >>= 1)
            ssum += __shfl_xor(ssum, off, 64);
        const float p = e / ssum;
        if (lane < LW) {
            sS[t * LP + lane] = p;
            attn_base[t * LW + lane] = p;
        }
    }
    __syncthreads();

    // ---- Phase 3: score[c][t] = sum_s P[t][s] * K[c][s]  (1x4 t-tiles) ----
    float* sc_base = score_out + (size_t)bh * (DK * LW);
    for (int u = tid; u < DK * 13; u += 256) {       // 416 units
        const int c  = u / 13;
        const int t4 = u - c * 13;
        const int t0 = t4 * 4;
        float a0 = 0.f, a1 = 0.f, a2 = 0.f, a3 = 0.f;
        #pragma unroll
        for (int s4 = 0; s4 < 13; s4++) {
            const float4 kv = *(const float4*)&sK[c * LP + 4 * s4];
            const float4 p0 = *(const float4*)&sS[(t0 + 0) * LP + 4 * s4];
            const float4 p1 = *(const float4*)&sS[(t0 + 1) * LP + 4 * s4];
            const float4 p2 = *(const float4*)&sS[(t0 + 2) * LP + 4 * s4];
            const float4 p3 = *(const float4*)&sS[(t0 + 3) * LP + 4 * s4];
            a0 = fmaf(p0.x, kv.x, a0); a0 = fmaf(p0.y, kv.y, a0);
            a0 = fmaf(p0.z, kv.z, a0); a0 = fmaf(p0.w, kv.w, a0);
            a1 = fmaf(p1.x, kv.x, a1); a1 = fmaf(p1.y, kv.y, a1);
            a1 = fmaf(p1.z, kv.z, a1); a1 = fmaf(p1.w, kv.w, a1);
            a2 = fmaf(p2.x, kv.x, a2); a2 = fmaf(p2.y, kv.y, a2);
            a2 = fmaf(p2.z, kv.z, a2); a2 = fmaf(p2.w, kv.w, a2);
            a3 = fmaf(p3.x, kv.x, a3); a3 = fmaf(p3.y, kv.y, a3);
            a3 = fmaf(p3.z, kv.z, a3); a3 = fmaf(p3.w, kv.w, a3);
        }
        if (t0 + 0 < LW) sc_base[c * LW + t0 + 0] = a0;
        if (t0 + 1 < LW) sc_base[c * LW + t0 + 1] = a1;
        if (t0 + 2 < LW) sc_base[c * LW + t0 + 2] = a2;
        if (t0 + 3 < LW) sc_base[c * LW + t0 + 3] = a3;
    }
}

extern "C" void kernel_launch(void* const* d_in, const int* in_sizes, int n_in,
                              void* d_out, int out_size, void* d_ws, size_t ws_size,
                              hipStream_t stream) {
    const float* q     = (const float*)d_in[0];
    const float* k     = (const float*)d_in[1];
    // d_in[2] = v, unused: reference reassigns v = k
    const float* mask  = (const float*)d_in[3];
    const float* table = (const float*)d_in[4];
    const int*   idx   = (const int*)d_in[5];

    float* score_out = (float*)d_out;
    float* attn_out  = score_out + (size_t)2048 * 256 * 49;   // 25,690,112

    wa_kernel<<<2048 * 8, 256, 0, stream>>>(q, k, mask, table, idx,
                                            score_out, attn_out);
}

// Round 2
// 682.976 us; speedup vs baseline: 2.1341x; 2.1341x over previous
//
#include <hip/hip_runtime.h>
#include <math.h>

// WindowAttention: B=2048, C=256, H=8, d_k=32, wh=ww=7 -> L=49, nW=64.
// Reference reassigns v = k: values come from K. Outputs: score (2048*256*49)
// then attn (2048*8*49*49), both fp32, concatenated in d_out.
//
// Design: one WAVE per (b,h). Lane t owns S-row t in registers (49 regs);
// softmax is fully in-lane. K is read via wave-uniform addresses -> scalar
// s_loads, used as SGPR operands in v_fmac (no LDS staging, no K VGPRs).
// Bias/mask pre-transposed to [s][t] layout in ws so their loads coalesce.
// attn rows transposed through one shared LDS buffer for coalesced writes.

#define LW 49
#define DK 32
#define NH 8

// ---------------- prep: maskT[w][s][t], biasT[h][s][t] in ws ----------------
__global__ __launch_bounds__(256) void prep_kernel(
    const float* __restrict__ mask, const float* __restrict__ table,
    const int* __restrict__ idx,
    float* __restrict__ maskT, float* __restrict__ biasT)
{
    const int i = blockIdx.x * 256 + threadIdx.x;
    const int LL = LW * LW;                 // 2401
    const int NM = 64 * LL;                 // 153664
    const int NB = NH * LL;                 // 19208
    if (i < NM) {
        const int w = i / LL;
        const int r = i - w * LL;
        const int s = r / LW;
        const int t = r - s * LW;
        maskT[i] = mask[w * LL + t * LW + s];          // coalesced write
    } else if (i < NM + NB) {
        const int j = i - NM;
        const int h = j / LL;
        const int r = j - h * LL;
        const int s = r / LW;
        const int t = r - s * LW;
        biasT[j] = table[idx[t * LW + s] * NH + h];    // coalesced write
    }
}

// ---------------- main: one wave per (b,h) ----------------
template<bool PREP>
__global__ __launch_bounds__(256, 4) void wa_wave_kernel(
    const float* __restrict__ q, const float* __restrict__ k,
    const float* __restrict__ maskT, const float* __restrict__ biasT,
    const float* __restrict__ mask0, const float* __restrict__ table,
    const int* __restrict__ idx,
    float* __restrict__ score_out, float* __restrict__ attn_out)
{
    __shared__ float sP[LW * LW];           // 9604 B, one transpose buffer

    const int lane = threadIdx.x & 63;
    const int wv   = __builtin_amdgcn_readfirstlane(threadIdx.x >> 6); // uniform!
    const int bh   = blockIdx.x * 4 + wv;   // uniform
    const int b    = bh >> 3;
    const int h    = bh & 7;
    const int w    = b & 63;
    const int t    = lane;
    const int tc   = (t < LW) ? t : (LW - 1);   // clamp for safe loads

    const float* qp = q + (size_t)bh * (DK * LW);   // uniform base
    const float* kp = k + (size_t)bh * (DK * LW);   // uniform base -> s_loads

    // ---- load Q column t (32 coalesced loads) ----
    float qreg[DK];
    #pragma unroll
    for (int c = 0; c < DK; c++) qreg[c] = qp[c * LW + tc];

    // ---- phase 1: S[s] = sum_c qreg[c] * K[c][s]  (K via SGPR operands) ----
    float S[LW];
    #pragma unroll
    for (int s = 0; s < LW; s++) S[s] = 0.f;
    #pragma unroll
    for (int c = 0; c < DK; c++) {
        #pragma unroll
        for (int s = 0; s < LW; s++)
            S[s] = fmaf(qreg[c], kp[c * LW + s], S[s]);
    }

    // ---- scale + bias + mask (coalesced via transposed layouts) ----
    const float scale = 0.17677669529663687f;       // 32^-0.5
    if (PREP) {
        const float* bt = biasT + (size_t)h * (LW * LW);
        const float* mt = maskT + (size_t)w * (LW * LW);
        #pragma unroll
        for (int s = 0; s < LW; s++) {
            const float bm = bt[s * LW + tc] + mt[s * LW + tc];
            S[s] = fmaf(S[s], scale, bm);
        }
    } else {
        // fallback (ws too small): scattered row reads, slower but correct
        const float* mrow = mask0 + (size_t)w * (LW * LW) + tc * LW;
        const int*   irow = idx + tc * LW;
        #pragma unroll
        for (int s = 0; s < LW; s++) {
            const float bm = table[irow[s] * NH + h] + mrow[s];
            S[s] = fmaf(S[s], scale, bm);
        }
    }

    // ---- in-lane softmax over s ----
    float m = S[0];
    #pragma unroll
    for (int s = 1; s < LW; s++) m = fmaxf(m, S[s]);
    float sum = 0.f;
    #pragma unroll
    for (int s = 0; s < LW; s++) { S[s] = __expf(S[s] - m); sum += S[s]; }
    const float inv = 1.0f / sum;
    #pragma unroll
    for (int s = 0; s < LW; s++) S[s] *= inv;

    // ---- attn write: transpose via shared sP (one wave at a time) ----
    float* attn_base = attn_out + (size_t)bh * (LW * LW);
    for (int turn = 0; turn < 4; turn++) {
        __syncthreads();
        if (turn == wv) {
            if (t < LW) {
                #pragma unroll
                for (int s = 0; s < LW; s++)
                    sP[t * LW + s] = S[s];      // stride-49: 2-way, free
            }
            #pragma unroll
            for (int it = 0; it < 38; it++) {
                const int i = it * 64 + lane;
                if (i < LW * LW) attn_base[i] = sP[i];   // coalesced b32
            }
        }
    }

    // ---- phase 3: score[c][t] = sum_s P[s] * K[c][s] ----
    float* sc = score_out + (size_t)bh * (DK * LW);
    #pragma unroll
    for (int c = 0; c < DK; c++) {
        float acc = 0.f;
        #pragma unroll
        for (int s = 0; s < LW; s++)
            acc = fmaf(S[s], kp[c * LW + s], acc);
        if (t < LW) sc[c * LW + t] = acc;       // coalesced
    }
}

extern "C" void kernel_launch(void* const* d_in, const int* in_sizes, int n_in,
                              void* d_out, int out_size, void* d_ws, size_t ws_size,
                              hipStream_t stream) {
    const float* q     = (const float*)d_in[0];
    const float* k     = (const float*)d_in[1];
    // d_in[2] = v, unused: reference reassigns v = k
    const float* mask  = (const float*)d_in[3];
    const float* table = (const float*)d_in[4];
    const int*   idx   = (const int*)d_in[5];

    float* score_out = (float*)d_out;
    float* attn_out  = score_out + (size_t)2048 * 256 * 49;

    const size_t NM = (size_t)64 * LW * LW;      // 153664 floats
    const size_t NB = (size_t)NH * LW * LW;      // 19208 floats
    const bool prep_ok = ws_size >= (NM + NB) * sizeof(float);

    if (prep_ok) {
        float* maskT = (float*)d_ws;
        float* biasT = maskT + NM;
        const int tot = (int)(NM + NB);
        prep_kernel<<<(tot + 255) / 256, 256, 0, stream>>>(mask, table, idx, maskT, biasT);
        wa_wave_kernel<true><<<4096, 256, 0, stream>>>(
            q, k, maskT, biasT, mask, table, idx, score_out, attn_out);
    } else {
        wa_wave_kernel<false><<<4096, 256, 0, stream>>>(
            q, k, q, q, mask, table, idx, score_out, attn_out);
    }
}